// Round 3
// baseline (157.255 us; speedup 1.0000x reference)
//
#include <hip/hip_runtime.h>
#include <math.h>

// Problem constants (fixed by reference setup_inputs)
#define NN 8192
#define SS 32
#define DD 32
#define KK 1024
#define OUT_ELEMS ((size_t)NN * SS * DD)   // 8388608; loss scalar at out[OUT_ELEMS]

// loss = S * (1 + BETA) * sum_sq / (N*S*D)
#define LOSS_SCALE (32.0f * 1.001f / 8388608.0f)

typedef _Float16 half8 __attribute__((ext_vector_type(8)));
typedef float   floatx4 __attribute__((ext_vector_type(4)));

#define NTILES 64                     // 1024 codewords / 16 per MFMA tile
#define RG 2                          // 16-row groups per wave -> 32 rows/wave
#define WAVES 16                      // 1024-thread blocks
#define BLK_ROWS (WAVES * RG * 16)    // 512 rows per block
#define NBLOCKS ((NN / BLK_ROWS) * SS) // 512 main blocks (1/CU resident, 2 rounds)

// SESSION NOTE (R9): R7 spilled (dur 347us). R8 (precomputed W + glload_lds
// staging + 8 barriers) was NEUTRAL vs R6: 80us, MfmaUtil pinned at 26% ==
// MFMA-floor(24.8us)/dur. Conclusion: the per-chunk {barrier -> lockstep
// ds_read -> dep-chain MFMA} rhythm itself is the stall; staging VALU and
// barrier count were never the critical path. This version: the ENTIRE per-s
// codebook (Wh 64KB + Wl 64KB + w2 4KB, pre-converted by w_pre) sits in LDS
// (137KB static, m201 precedent) -> K-loop has ZERO barriers and ZERO LDS
// writes; waves free-run; compiler may hoist ds_reads freely (no hazards).
// 1024-thr blocks, 16 waves, 1 block/CU, 512 blocks in 2 rounds.

// ---- workspace layout (d_ws): needs ~4.14 MB ----
#define W2P_OFF  4096                          // part[NBLOCKS] lives at 0
#define WHP_OFF  (W2P_OFF + SS * KK * 4)       // w2P: 128 KB
#define WLP_OFF  (WHP_OFF + SS * KK * DD * 2)  // WhP: 2 MB, WlP: 2 MB

typedef const __attribute__((address_space(1))) void* gas_p;
typedef __attribute__((address_space(3))) void* las_p;

__device__ __forceinline__ void gll16(const void* g, void* l) {
    __builtin_amdgcn_global_load_lds((gas_p)g, (las_p)l, 16, 0, 0);
}
__device__ __forceinline__ void gll4(const void* g, void* l) {
    __builtin_amdgcn_global_load_lds((gas_p)g, (las_p)l, 4, 0, 0);
}

// ---- one-time W preprocessing: f16 hi/lo split + row norms, fragment order ----
// WhP/WlP layout: [s][tile g=0..63][lane l=0..63][8 halves]; the 16B group at
// (s,g,l) holds codeword k = g*16 + (l&15), dims d = (l>>4)*8..+7.
__global__ __launch_bounds__(256) void w_pre(const float* __restrict__ W,
                                             _Float16* __restrict__ WhP,
                                             _Float16* __restrict__ WlP,
                                             float* __restrict__ w2P) {
    const int u    = blockIdx.x * 256 + threadIdx.x;   // 0..131071
    const int s    = u >> 12;
    const int g    = (u >> 6) & 63;
    const int l    = u & 63;
    const int col  = l & 15;
    const int quad = l >> 4;
    const int k    = g * 16 + col;
    const float* src = W + ((size_t)s * KK + k) * DD + quad * 8;
    const float4 va = ((const float4*)src)[0];
    const float4 vb = ((const float4*)src)[1];
    const float v[8] = {va.x, va.y, va.z, va.w, vb.x, vb.y, vb.z, vb.w};
    half8 h8, l8; float ps = 0.0f;
    #pragma unroll
    for (int j = 0; j < 8; ++j) {
        const float x = v[j];
        ps = fmaf(x, x, ps);
        const _Float16 h = (_Float16)x;
        h8[j] = h;
        l8[j] = (_Float16)(x - (float)h);
    }
    ps += __shfl_xor(ps, 16, 64);
    ps += __shfl_xor(ps, 32, 64);
    *(half8*)(WhP + (size_t)u * 8) = h8;
    *(half8*)(WlP + (size_t)u * 8) = l8;
    if (quad == 0) w2P[s * KK + k] = ps;   // w2P[s][k] linear
}

__global__ __launch_bounds__(1024, 4) void vq_fused(const float* __restrict__ z,
                                                    const float* __restrict__ W,
                                                    const _Float16* __restrict__ WhP,
                                                    const _Float16* __restrict__ WlP,
                                                    const float* __restrict__ w2P,
                                                    float* __restrict__ out,
                                                    float* __restrict__ part) {
    // Whole per-s codebook resident in LDS. 137.3 KB static (<160 KB).
    __shared__ _Float16 bufH[NTILES][64][8];   // 64 KB
    __shared__ _Float16 bufL[NTILES][64][8];   // 64 KB
    __shared__ float    w2b[KK];               // 4 KB
    __shared__ int      lds_idx[WAVES][32];    // 2 KB
    __shared__ float    lds_part[WAVES];

    const int s    = blockIdx.x & (SS - 1);
    const int n0b  = (blockIdx.x >> 5) * BLK_ROWS;
    const int tid  = threadIdx.x;
    const int wv   = tid >> 6;
    const int lane = tid & 63;
    const int col  = lane & 15;
    const int quad = lane >> 4;

    const float* __restrict__ Ws = W + (size_t)s * KK * DD;
    const int n0w = n0b + wv * (RG * 16);

    // ---- stage the whole codebook: 16 gll16 + 1 gll4 per thread-group ----
    // m104 rule: LDS dest = wave-uniform base; HW adds lane*width.
    {
        const char* gH = (const char*)(WhP + (size_t)s * (NTILES * 512));
        const char* gL = (const char*)(WlP + (size_t)s * (NTILES * 512));
        char* lH = (char*)&bufH[0][0][0];
        char* lL = (char*)&bufL[0][0][0];
        const int wvB = wv * 1024;             // 64 lanes * 16 B
        #pragma unroll
        for (int i = 0; i < 4; ++i) {
            const int off = i * 16384 + wvB;
            gll16(gH + off + lane * 16, lH + off);
            gll16(gL + off + lane * 16, lL + off);
        }
        const float* g2 = w2P + (size_t)s * KK + wv * 64;
        gll4(g2 + lane, (char*)w2b + wv * 256);
    }

    // ---- A-fragments: (-2*z) split into f16 hi/lo (overlaps the staging) ----
    half8 zh[RG], zl[RG];
    #pragma unroll
    for (int rg = 0; rg < RG; ++rg) {
        const float* zp = z + (size_t)(n0w + rg * 16 + col) * (SS * DD) + s * DD + quad * 8;
        const float4 va = ((const float4*)zp)[0];
        const float4 vb = ((const float4*)zp)[1];
        const float src[8] = {va.x, va.y, va.z, va.w, vb.x, vb.y, vb.z, vb.w};
        #pragma unroll
        for (int j = 0; j < 8; ++j) {
            const float v = -2.0f * src[j];
            const _Float16 h = (_Float16)v;
            zh[rg][j] = h;
            zl[rg][j] = (_Float16)(v - (float)h);
        }
    }

    floatx4 best[RG];
    int bi[RG][4];
    #pragma unroll
    for (int rg = 0; rg < RG; ++rg) {
        best[rg] = (floatx4){INFINITY, INFINITY, INFINITY, INFINITY};
        bi[rg][0] = bi[rg][1] = bi[rg][2] = bi[rg][3] = 0;
    }

    __syncthreads();   // single barrier: drains gll vmcnt; codebook visible

    // ---- K loop: 64 tiles, pure ds_read + MFMA + compare. No barriers,
    // no LDS writes -> waves free-run, reads hoistable. ----
    #pragma unroll 8
    for (int tt = 0; tt < NTILES; ++tt) {
        const half8 bh = *(const half8*)&bufH[tt][lane][0];
        const half8 bl = *(const half8*)&bufL[tt][lane][0];
        const float w2v = w2b[tt * 16 + col];
        const floatx4 c0 = {w2v, w2v, w2v, w2v};
        __builtin_amdgcn_s_setprio(1);
        floatx4 a0 = __builtin_amdgcn_mfma_f32_16x16x32_f16(zh[0], bh, c0, 0, 0, 0);
        floatx4 a1 = __builtin_amdgcn_mfma_f32_16x16x32_f16(zh[1], bh, c0, 0, 0, 0);
        a0 = __builtin_amdgcn_mfma_f32_16x16x32_f16(zl[0], bh, a0, 0, 0, 0);
        a1 = __builtin_amdgcn_mfma_f32_16x16x32_f16(zl[1], bh, a1, 0, 0, 0);
        a0 = __builtin_amdgcn_mfma_f32_16x16x32_f16(zh[0], bl, a0, 0, 0, 0);
        a1 = __builtin_amdgcn_mfma_f32_16x16x32_f16(zh[1], bl, a1, 0, 0, 0);
        __builtin_amdgcn_s_setprio(0);
        #pragma unroll
        for (int i = 0; i < 4; ++i) {   // strict <, lowest tile wins ties
            if (a0[i] < best[0][i]) { best[0][i] = a0[i]; bi[0][i] = tt; }
            if (a1[i] < best[1][i]) { best[1][i] = a1[i]; bi[1][i] = tt; }
        }
    }

    // ---- cross-lane argmin over the 16 k-columns; lower k wins ties ----
    #pragma unroll
    for (int rg = 0; rg < RG; ++rg) {
        #pragma unroll
        for (int i = 0; i < 4; ++i) {
            float v = best[rg][i];
            int   k = bi[rg][i] * 16 + col;
            #pragma unroll
            for (int m = 1; m < 16; m <<= 1) {
                const float vo = __shfl_xor(v, m, 64);
                const int   ko = __shfl_xor(k, m, 64);
                if (vo < v || (vo == v && ko < k)) { v = vo; k = ko; }
            }
            if (col == 0) lds_idx[wv][rg * 16 + quad * 4 + i] = k;  // row-in-wave
        }
    }
    __syncthreads();

    // ---- epilogue: 2 lanes per n-row (16 floats each); zq = fp32 W[s,k*] ----
    const int r  = lane & 31;
    const int dh = (lane >> 5) * 16;
    const int krow = lds_idx[wv][r];
    const float* wsrc = Ws + (size_t)krow * DD + dh;
    const size_t zoff = (size_t)(n0w + r) * (SS * DD) + s * DD + dh;
    const float* zsrc = z + zoff;
    float* od = out + zoff;
    float sq = 0.0f;
    #pragma unroll
    for (int cc = 0; cc < 4; ++cc) {
        const float4 wq = ((const float4*)wsrc)[cc];
        const float4 zv = ((const float4*)zsrc)[cc];
        const float d0 = wq.x - zv.x, d1 = wq.y - zv.y;
        const float d2 = wq.z - zv.z, d3 = wq.w - zv.w;
        sq = fmaf(d0, d0, sq); sq = fmaf(d1, d1, sq);
        sq = fmaf(d2, d2, sq); sq = fmaf(d3, d3, sq);
        ((float4*)od)[cc] = wq;
    }
    #pragma unroll
    for (int off = 32; off > 0; off >>= 1) sq += __shfl_down(sq, off, 64);

    // per-block partial -> distinct address; NO same-address atomics
    if (lane == 0) lds_part[wv] = sq;
    __syncthreads();
    if (tid == 0) {
        float t = 0.0f;
        #pragma unroll
        for (int w = 0; w < WAVES; ++w) t += lds_part[w];
        part[blockIdx.x] = t;
    }
}

// Tiny final reduce: 1 block sums the per-block partials.
__global__ __launch_bounds__(256) void vq_loss(const float* __restrict__ part,
                                               float* __restrict__ out) {
    __shared__ float l[4];
    const int tid = threadIdx.x;
    float sum = 0.0f;
    #pragma unroll
    for (int i = 0; i < NBLOCKS / 256; ++i) sum += part[tid + i * 256];
    #pragma unroll
    for (int off = 32; off > 0; off >>= 1) sum += __shfl_down(sum, off, 64);
    if ((tid & 63) == 0) l[tid >> 6] = sum;
    __syncthreads();
    if (tid == 0) out[OUT_ELEMS] = (l[0] + l[1] + l[2] + l[3]) * LOSS_SCALE;
}

extern "C" void kernel_launch(void* const* d_in, const int* in_sizes, int n_in,
                              void* d_out, int out_size, void* d_ws, size_t ws_size,
                              hipStream_t stream) {
    const float* z = (const float*)d_in[0];   // (8192, 1024) fp32
    const float* W = (const float*)d_in[1];   // (32, 1024, 32) fp32
    float* out  = (float*)d_out;              // 8388608 zq_st + 1 loss

    char* ws = (char*)d_ws;                   // needs ~4.14 MB
    float*    part = (float*)ws;              // [0, 4KB)
    float*    w2P  = (float*)(ws + W2P_OFF);  // 128 KB
    _Float16* WhP  = (_Float16*)(ws + WHP_OFF); // 2 MB
    _Float16* WlP  = (_Float16*)(ws + WLP_OFF); // 2 MB

    // one-time W split (4 MB read): 131072 threads
    w_pre<<<dim3(512), dim3(256), 0, stream>>>(W, WhP, WlP, w2P);
    // 512 blocks: blockIdx&31 = s, blockIdx>>5 = 512-row n-tile.
    vq_fused<<<dim3(NBLOCKS), dim3(1024), 0, stream>>>(z, W, WhP, WlP, w2P, out, part);
    vq_loss<<<dim3(1), dim3(256), 0, stream>>>(part, out);
}

// Round 4
// 154.433 us; speedup vs baseline: 1.0183x; 1.0183x over previous
//
#include <hip/hip_runtime.h>
#include <math.h>

// Problem constants (fixed by reference setup_inputs)
#define NN 8192
#define SS 32
#define DD 32
#define KK 1024
#define OUT_ELEMS ((size_t)NN * SS * DD)   // 8388608; loss scalar at out[OUT_ELEMS]

// loss = S * (1 + BETA) * sum_sq / (N*S*D)
#define LOSS_SCALE (32.0f * 1.001f / 8388608.0f)

typedef _Float16 half8 __attribute__((ext_vector_type(8)));
typedef float   floatx4 __attribute__((ext_vector_type(4)));

#define NTILES 64                     // 1024 codewords / 16 per MFMA tile
#define RG 2                          // 16-row groups per wave -> 32 rows/wave
#define WAVES 16                      // 1024-thread blocks
#define BLK_ROWS (WAVES * RG * 16)    // 512 rows per block
#define NBLOCKS ((NN / BLK_ROWS) * SS) // 512 main blocks (1/CU, 2 rounds)

// SESSION NOTE (R10): R6/R8/R9 (three different schedules: lockstep-dbuf,
// glload-staged, LDS-resident barrier-free) ALL land at 80-90us, MfmaUtil
// ~25%, dur insensitive to occupancy 16->32 waves/CU. Common denominator:
// per-tile closed latency chain ds_read -> 3-dep MFMA -> dependent compares
// (compiler sinks everything; VGPR 44-52 = no pipelining ever happened).
// This version pipelines BY CONSTRUCTION: loop body does load(t+1) ||
// MFMA(t) || compare(t-1) on a manual A/B register rotation -- nothing in an
// iteration consumes same-iteration results, so waves never stall on their
// own MFMA/LDS latency. No setprio (proven irrelevant). unroll 2 (I$-safe).

// ---- workspace layout (d_ws): needs ~4.14 MB ----
#define W2P_OFF  4096                          // part[NBLOCKS] lives at 0
#define WHP_OFF  (W2P_OFF + SS * KK * 4)       // w2P: 128 KB
#define WLP_OFF  (WHP_OFF + SS * KK * DD * 2)  // WhP: 2 MB, WlP: 2 MB

typedef const __attribute__((address_space(1))) void* gas_p;
typedef __attribute__((address_space(3))) void* las_p;

__device__ __forceinline__ void gll16(const void* g, void* l) {
    __builtin_amdgcn_global_load_lds((gas_p)g, (las_p)l, 16, 0, 0);
}
__device__ __forceinline__ void gll4(const void* g, void* l) {
    __builtin_amdgcn_global_load_lds((gas_p)g, (las_p)l, 4, 0, 0);
}

#define MFMA16(a, b, c) __builtin_amdgcn_mfma_f32_16x16x32_f16((a), (b), (c), 0, 0, 0)

// ---- one-time W preprocessing: f16 hi/lo split + row norms, fragment order ----
// WhP/WlP layout: [s][tile g=0..63][lane l=0..63][8 halves]; the 16B group at
// (s,g,l) holds codeword k = g*16 + (l&15), dims d = (l>>4)*8..+7.
__global__ __launch_bounds__(256) void w_pre(const float* __restrict__ W,
                                             _Float16* __restrict__ WhP,
                                             _Float16* __restrict__ WlP,
                                             float* __restrict__ w2P) {
    const int u    = blockIdx.x * 256 + threadIdx.x;   // 0..131071
    const int s    = u >> 12;
    const int g    = (u >> 6) & 63;
    const int l    = u & 63;
    const int col  = l & 15;
    const int quad = l >> 4;
    const int k    = g * 16 + col;
    const float* src = W + ((size_t)s * KK + k) * DD + quad * 8;
    const float4 va = ((const float4*)src)[0];
    const float4 vb = ((const float4*)src)[1];
    const float v[8] = {va.x, va.y, va.z, va.w, vb.x, vb.y, vb.z, vb.w};
    half8 h8, l8; float ps = 0.0f;
    #pragma unroll
    for (int j = 0; j < 8; ++j) {
        const float x = v[j];
        ps = fmaf(x, x, ps);
        const _Float16 h = (_Float16)x;
        h8[j] = h;
        l8[j] = (_Float16)(x - (float)h);
    }
    ps += __shfl_xor(ps, 16, 64);
    ps += __shfl_xor(ps, 32, 64);
    *(half8*)(WhP + (size_t)u * 8) = h8;
    *(half8*)(WlP + (size_t)u * 8) = l8;
    if (quad == 0) w2P[s * KK + k] = ps;   // w2P[s][k] linear
}

__global__ __launch_bounds__(1024, 4) void vq_fused(const float* __restrict__ z,
                                                    const float* __restrict__ W,
                                                    const _Float16* __restrict__ WhP,
                                                    const _Float16* __restrict__ WlP,
                                                    const float* __restrict__ w2P,
                                                    float* __restrict__ out,
                                                    float* __restrict__ part) {
    // Whole per-s codebook resident in LDS. 137.3 KB static (<160 KB).
    __shared__ _Float16 bufH[NTILES][64][8];   // 64 KB
    __shared__ _Float16 bufL[NTILES][64][8];   // 64 KB
    __shared__ float    w2b[KK];               // 4 KB
    __shared__ int      lds_idx[WAVES][32];    // 2 KB
    __shared__ float    lds_part[WAVES];

    const int s    = blockIdx.x & (SS - 1);
    const int n0b  = (blockIdx.x >> 5) * BLK_ROWS;
    const int tid  = threadIdx.x;
    const int wv   = tid >> 6;
    const int lane = tid & 63;
    const int col  = lane & 15;
    const int quad = lane >> 4;

    const float* __restrict__ Ws = W + (size_t)s * KK * DD;
    const int n0w = n0b + wv * (RG * 16);

    // ---- stage the whole codebook: 8 gll16 + 1 gll4 per wave ----
    // m104 rule: LDS dest = wave-uniform base; HW adds lane*width.
    {
        const char* gH = (const char*)(WhP + (size_t)s * (NTILES * 512));
        const char* gL = (const char*)(WlP + (size_t)s * (NTILES * 512));
        char* lH = (char*)&bufH[0][0][0];
        char* lL = (char*)&bufL[0][0][0];
        const int wvB = wv * 1024;             // 64 lanes * 16 B
        #pragma unroll
        for (int i = 0; i < 4; ++i) {
            const int off = i * 16384 + wvB;
            gll16(gH + off + lane * 16, lH + off);
            gll16(gL + off + lane * 16, lL + off);
        }
        const float* g2 = w2P + (size_t)s * KK + wv * 64;
        gll4(g2 + lane, (char*)w2b + wv * 256);
    }

    // ---- A-fragments: (-2*z) split into f16 hi/lo (overlaps the staging) ----
    half8 zh[RG], zl[RG];
    #pragma unroll
    for (int rg = 0; rg < RG; ++rg) {
        const float* zp = z + (size_t)(n0w + rg * 16 + col) * (SS * DD) + s * DD + quad * 8;
        const float4 va = ((const float4*)zp)[0];
        const float4 vb = ((const float4*)zp)[1];
        const float src[8] = {va.x, va.y, va.z, va.w, vb.x, vb.y, vb.z, vb.w};
        #pragma unroll
        for (int j = 0; j < 8; ++j) {
            const float v = -2.0f * src[j];
            const _Float16 h = (_Float16)v;
            zh[rg][j] = h;
            zl[rg][j] = (_Float16)(v - (float)h);
        }
    }

    floatx4 best[RG];
    int bi[RG][4];
    #pragma unroll
    for (int rg = 0; rg < RG; ++rg) {
        best[rg] = (floatx4){INFINITY, INFINITY, INFINITY, INFINITY};
        bi[rg][0] = bi[rg][1] = bi[rg][2] = bi[rg][3] = 0;
    }

    __syncthreads();   // single barrier: drains gll vmcnt; codebook visible

    // ---- K loop: software-pipelined with 1-tile offset.
    // Each half-body: load frags(t+1) || MFMA(t) || compare(t-1).
    // Manual A/B rotation (named vars only -> registers, rule #20). ----
    half8 fhA = *(const half8*)&bufH[0][lane][0];
    half8 flA = *(const half8*)&bufL[0][lane][0];
    float w2A = w2b[col];
    half8 fhB, flB; float w2B;
    floatx4 pA0, pA1, pB0, pB1;
    pB0 = pB1 = (floatx4){INFINITY, INFINITY, INFINITY, INFINITY};

    #pragma unroll 2
    for (int t = 0; t < NTILES; t += 2) {
        // ---- even half: load t+1 -> B; MFMA t (A); compare t-1 (pB) ----
        fhB = *(const half8*)&bufH[t + 1][lane][0];
        flB = *(const half8*)&bufL[t + 1][lane][0];
        w2B = w2b[(t + 1) * 16 + col];
        {
            const floatx4 c0 = {w2A, w2A, w2A, w2A};
            pA0 = MFMA16(zh[0], fhA, c0);
            pA1 = MFMA16(zh[1], fhA, c0);
            pA0 = MFMA16(zl[0], fhA, pA0);
            pA1 = MFMA16(zl[1], fhA, pA1);
            pA0 = MFMA16(zh[0], flA, pA0);
            pA1 = MFMA16(zh[1], flA, pA1);
        }
        {
            const int tk = t - 1;   // t=0: INF sentinel, never wins (INF<INF false)
            #pragma unroll
            for (int i = 0; i < 4; ++i) {   // strict <, lowest tile wins ties
                if (pB0[i] < best[0][i]) { best[0][i] = pB0[i]; bi[0][i] = tk; }
                if (pB1[i] < best[1][i]) { best[1][i] = pB1[i]; bi[1][i] = tk; }
            }
        }
        // ---- odd half: load t+2 -> A; MFMA t+1 (B); compare t (pA) ----
        const int t2 = (t + 2) & (NTILES - 1);   // wraps to 0 on last iter (unused)
        fhA = *(const half8*)&bufH[t2][lane][0];
        flA = *(const half8*)&bufL[t2][lane][0];
        w2A = w2b[t2 * 16 + col];
        {
            const floatx4 c0 = {w2B, w2B, w2B, w2B};
            pB0 = MFMA16(zh[0], fhB, c0);
            pB1 = MFMA16(zh[1], fhB, c0);
            pB0 = MFMA16(zl[0], fhB, pB0);
            pB1 = MFMA16(zl[1], fhB, pB1);
            pB0 = MFMA16(zh[0], flB, pB0);
            pB1 = MFMA16(zh[1], flB, pB1);
        }
        {
            const int tk = t;
            #pragma unroll
            for (int i = 0; i < 4; ++i) {
                if (pA0[i] < best[0][i]) { best[0][i] = pA0[i]; bi[0][i] = tk; }
                if (pA1[i] < best[1][i]) { best[1][i] = pA1[i]; bi[1][i] = tk; }
            }
        }
    }
    {   // drain: compare last tile (pB, tile NTILES-1)
        const int tk = NTILES - 1;
        #pragma unroll
        for (int i = 0; i < 4; ++i) {
            if (pB0[i] < best[0][i]) { best[0][i] = pB0[i]; bi[0][i] = tk; }
            if (pB1[i] < best[1][i]) { best[1][i] = pB1[i]; bi[1][i] = tk; }
        }
    }

    // ---- cross-lane argmin over the 16 k-columns; lower k wins ties ----
    #pragma unroll
    for (int rg = 0; rg < RG; ++rg) {
        #pragma unroll
        for (int i = 0; i < 4; ++i) {
            float v = best[rg][i];
            int   k = bi[rg][i] * 16 + col;
            #pragma unroll
            for (int m = 1; m < 16; m <<= 1) {
                const float vo = __shfl_xor(v, m, 64);
                const int   ko = __shfl_xor(k, m, 64);
                if (vo < v || (vo == v && ko < k)) { v = vo; k = ko; }
            }
            if (col == 0) lds_idx[wv][rg * 16 + quad * 4 + i] = k;  // row-in-wave
        }
    }
    __syncthreads();

    // ---- epilogue: 2 lanes per n-row (16 floats each); zq = fp32 W[s,k*] ----
    const int r  = lane & 31;
    const int dh = (lane >> 5) * 16;
    const int krow = lds_idx[wv][r];
    const float* wsrc = Ws + (size_t)krow * DD + dh;
    const size_t zoff = (size_t)(n0w + r) * (SS * DD) + s * DD + dh;
    const float* zsrc = z + zoff;
    float* od = out + zoff;
    float sq = 0.0f;
    #pragma unroll
    for (int cc = 0; cc < 4; ++cc) {
        const float4 wq = ((const float4*)wsrc)[cc];
        const float4 zv = ((const float4*)zsrc)[cc];
        const float d0 = wq.x - zv.x, d1 = wq.y - zv.y;
        const float d2 = wq.z - zv.z, d3 = wq.w - zv.w;
        sq = fmaf(d0, d0, sq); sq = fmaf(d1, d1, sq);
        sq = fmaf(d2, d2, sq); sq = fmaf(d3, d3, sq);
        ((float4*)od)[cc] = wq;
    }
    #pragma unroll
    for (int off = 32; off > 0; off >>= 1) sq += __shfl_down(sq, off, 64);

    // per-block partial -> distinct address; NO same-address atomics
    if (lane == 0) lds_part[wv] = sq;
    __syncthreads();
    if (tid == 0) {
        float t = 0.0f;
        #pragma unroll
        for (int w = 0; w < WAVES; ++w) t += lds_part[w];
        part[blockIdx.x] = t;
    }
}

// Tiny final reduce: 1 block sums the per-block partials.
__global__ __launch_bounds__(256) void vq_loss(const float* __restrict__ part,
                                               float* __restrict__ out) {
    __shared__ float l[4];
    const int tid = threadIdx.x;
    float sum = 0.0f;
    #pragma unroll
    for (int i = 0; i < NBLOCKS / 256; ++i) sum += part[tid + i * 256];
    #pragma unroll
    for (int off = 32; off > 0; off >>= 1) sum += __shfl_down(sum, off, 64);
    if ((tid & 63) == 0) l[tid >> 6] = sum;
    __syncthreads();
    if (tid == 0) out[OUT_ELEMS] = (l[0] + l[1] + l[2] + l[3]) * LOSS_SCALE;
}

extern "C" void kernel_launch(void* const* d_in, const int* in_sizes, int n_in,
                              void* d_out, int out_size, void* d_ws, size_t ws_size,
                              hipStream_t stream) {
    const float* z = (const float*)d_in[0];   // (8192, 1024) fp32
    const float* W = (const float*)d_in[1];   // (32, 1024, 32) fp32
    float* out  = (float*)d_out;              // 8388608 zq_st + 1 loss

    char* ws = (char*)d_ws;                   // needs ~4.14 MB
    float*    part = (float*)ws;              // [0, 4KB)
    float*    w2P  = (float*)(ws + W2P_OFF);  // 128 KB
    _Float16* WhP  = (_Float16*)(ws + WHP_OFF); // 2 MB
    _Float16* WlP  = (_Float16*)(ws + WLP_OFF); // 2 MB

    // one-time W split (4 MB read): 131072 threads
    w_pre<<<dim3(512), dim3(256), 0, stream>>>(W, WhP, WlP, w2P);
    // 512 blocks: blockIdx&31 = s, blockIdx>>5 = 512-row n-tile.
    vq_fused<<<dim3(NBLOCKS), dim3(1024), 0, stream>>>(z, W, WhP, WlP, w2P, out, part);
    vq_loss<<<dim3(1), dim3(256), 0, stream>>>(part, out);
}